// Round 1
// baseline (677.491 us; speedup 1.0000x reference)
//
#include <hip/hip_runtime.h>
#include <math.h>

// approxmatch EMD (Fan et al.) — b=8, n=m=2048, f32.
// Decomposition per annealing level (no match / d2 materialization):
//   A (rows): f_i = remainL_i / (1e-9 + sum_j exp(k*d2_ij)*R_j)
//   B (cols): s_j = sum_i f_i*exp(k*d2_ij); colsum=R_j*s_j;
//             r_j = min(R_j/(1e-9+colsum),1); c_j = R_j*r_j;
//             remainR_j = max(R_j - colsum*r_j, 0)
//   C (rows): t_i = sum_j exp*c_j; u_i = sum_j exp*c_j*sqrt(d2);
//             remainL_i = max(remainL_i - f_i*t_i, 0); costrow_i += f_i*u_i
// Points + per-point weight packed as float4 in LDS; d2 recomputed on the fly.

#define BLOCK 256
#define RPW 2   // rows (or cols) per wave

__device__ __forceinline__ float wave_reduce(float v) {
#pragma unroll
    for (int off = 32; off > 0; off >>= 1)
        v += __shfl_down(v, off, 64);
    return v;
}

__global__ void k_init(float* remainL, float* remainR, float* costrow,
                       int bn, int bm, float multiL, float multiR) {
    int i = blockIdx.x * blockDim.x + threadIdx.x;
    if (i < bn) { remainL[i] = multiL; costrow[i] = 0.f; }
    if (i < bm) remainR[i] = multiR;
}

// Pass A: compute f_i
__global__ void k_rowA(const float* __restrict__ xyz1,
                       const float* __restrict__ xyz2,
                       const float* __restrict__ remainL,
                       const float* __restrict__ remainR,
                       float* __restrict__ f,
                       int n, int m, float k) {
    extern __shared__ float4 sh[];            // (x2,y2,z2,R_j) per column
    const int rpb = (BLOCK / 64) * RPW;       // rows per block
    const int row0 = blockIdx.x * rpb;        // flat row index (batch*n + i)
    const int batch = row0 / n;               // n % rpb == 0 -> block in one batch
    const float* x2 = xyz2 + (size_t)batch * m * 3;
    const float* R  = remainR + (size_t)batch * m;
    for (int j = threadIdx.x; j < m; j += BLOCK)
        sh[j] = make_float4(x2[3*j], x2[3*j+1], x2[3*j+2], R[j]);
    __syncthreads();
    const int wave = threadIdx.x >> 6, lane = threadIdx.x & 63;
    const int r0 = row0 + wave * RPW;
    float px[RPW], py[RPW], pz[RPW], acc[RPW];
#pragma unroll
    for (int r = 0; r < RPW; ++r) {
        const float* p = xyz1 + (size_t)(r0 + r) * 3;
        px[r] = p[0]; py[r] = p[1]; pz[r] = p[2];
        acc[r] = 0.f;
    }
    for (int j = lane; j < m; j += 64) {
        float4 q = sh[j];
#pragma unroll
        for (int r = 0; r < RPW; ++r) {
            float dx = px[r]-q.x, dy = py[r]-q.y, dz = pz[r]-q.z;
            float d2 = dx*dx + dy*dy + dz*dz;
            acc[r] += q.w * exp2f(k * d2);
        }
    }
#pragma unroll
    for (int r = 0; r < RPW; ++r) {
        float s = wave_reduce(acc[r]);
        if (lane == 0) f[r0+r] = remainL[r0+r] / (1e-9f + s);
    }
}

// Pass B: compute c_j, update remainR_j
__global__ void k_colB(const float* __restrict__ xyz1,
                       const float* __restrict__ xyz2,
                       const float* __restrict__ f,
                       float* __restrict__ remainR,
                       float* __restrict__ c,
                       int n, int m, float k) {
    extern __shared__ float4 sh[];            // (x1,y1,z1,f_i) per row
    const int cpb = (BLOCK / 64) * RPW;
    const int col0 = blockIdx.x * cpb;        // flat col index (batch*m + j)
    const int batch = col0 / m;
    const float* x1 = xyz1 + (size_t)batch * n * 3;
    const float* F  = f + (size_t)batch * n;
    for (int i = threadIdx.x; i < n; i += BLOCK)
        sh[i] = make_float4(x1[3*i], x1[3*i+1], x1[3*i+2], F[i]);
    __syncthreads();
    const int wave = threadIdx.x >> 6, lane = threadIdx.x & 63;
    const int c0 = col0 + wave * RPW;
    float px[RPW], py[RPW], pz[RPW], acc[RPW];
#pragma unroll
    for (int r = 0; r < RPW; ++r) {
        const float* p = xyz2 + (size_t)(c0 + r) * 3;
        px[r] = p[0]; py[r] = p[1]; pz[r] = p[2];
        acc[r] = 0.f;
    }
    for (int i = lane; i < n; i += 64) {
        float4 q = sh[i];
#pragma unroll
        for (int r = 0; r < RPW; ++r) {
            float dx = px[r]-q.x, dy = py[r]-q.y, dz = pz[r]-q.z;
            float d2 = dx*dx + dy*dy + dz*dz;
            acc[r] += q.w * exp2f(k * d2);
        }
    }
#pragma unroll
    for (int r = 0; r < RPW; ++r) {
        float s = wave_reduce(acc[r]);
        if (lane == 0) {
            int gj = c0 + r;
            float R = remainR[gj];
            float colsum = R * s;
            float rr = fminf(R / (1e-9f + colsum), 1.0f);
            c[gj] = R * rr;
            remainR[gj] = fmaxf(R - colsum * rr, 0.f);
        }
    }
}

// Pass C: update remainL_i, accumulate per-row cost
__global__ void k_rowC(const float* __restrict__ xyz1,
                       const float* __restrict__ xyz2,
                       const float* __restrict__ f,
                       const float* __restrict__ c,
                       float* __restrict__ remainL,
                       float* __restrict__ costrow,
                       int n, int m, float k) {
    extern __shared__ float4 sh[];            // (x2,y2,z2,c_j) per column
    const int rpb = (BLOCK / 64) * RPW;
    const int row0 = blockIdx.x * rpb;
    const int batch = row0 / n;
    const float* x2 = xyz2 + (size_t)batch * m * 3;
    const float* C  = c + (size_t)batch * m;
    for (int j = threadIdx.x; j < m; j += BLOCK)
        sh[j] = make_float4(x2[3*j], x2[3*j+1], x2[3*j+2], C[j]);
    __syncthreads();
    const int wave = threadIdx.x >> 6, lane = threadIdx.x & 63;
    const int r0 = row0 + wave * RPW;
    float px[RPW], py[RPW], pz[RPW], accT[RPW], accU[RPW];
#pragma unroll
    for (int r = 0; r < RPW; ++r) {
        const float* p = xyz1 + (size_t)(r0 + r) * 3;
        px[r] = p[0]; py[r] = p[1]; pz[r] = p[2];
        accT[r] = 0.f; accU[r] = 0.f;
    }
    for (int j = lane; j < m; j += 64) {
        float4 q = sh[j];
#pragma unroll
        for (int r = 0; r < RPW; ++r) {
            float dx = px[r]-q.x, dy = py[r]-q.y, dz = pz[r]-q.z;
            float d2 = dx*dx + dy*dy + dz*dz;
            float e = q.w * exp2f(k * d2);
            accT[r] += e;
            accU[r] += e * sqrtf(fmaxf(d2, 1e-30f));
        }
    }
#pragma unroll
    for (int r = 0; r < RPW; ++r) {
        float t = wave_reduce(accT[r]);
        float u = wave_reduce(accU[r]);
        if (lane == 0) {
            int gi = r0 + r;
            float fi = f[gi];
            remainL[gi] = fmaxf(remainL[gi] - fi * t, 0.f);
            costrow[gi] += fi * u;
        }
    }
}

__global__ void k_cost(const float* __restrict__ costrow,
                       float* __restrict__ out, int n) {
    __shared__ float ws[BLOCK / 64];
    const float* cr = costrow + (size_t)blockIdx.x * n;
    float s = 0.f;
    for (int i = threadIdx.x; i < n; i += BLOCK) s += cr[i];
    s = wave_reduce(s);
    int wave = threadIdx.x >> 6, lane = threadIdx.x & 63;
    if (lane == 0) ws[wave] = s;
    __syncthreads();
    if (threadIdx.x == 0) {
        float t = 0.f;
#pragma unroll
        for (int w = 0; w < BLOCK / 64; ++w) t += ws[w];
        out[blockIdx.x] = t;
    }
}

extern "C" void kernel_launch(void* const* d_in, const int* in_sizes, int n_in,
                              void* d_out, int out_size, void* d_ws, size_t ws_size,
                              hipStream_t stream) {
    const float* xyz1 = (const float*)d_in[0];
    const float* xyz2 = (const float*)d_in[1];
    float* out = (float*)d_out;
    const int b = out_size;                 // one cost per batch
    const int n = in_sizes[0] / (3 * b);
    const int m = in_sizes[1] / (3 * b);
    const int bn = b * n, bm = b * m;

    float* ws      = (float*)d_ws;
    float* remainL = ws;                    // bn
    float* remainR = remainL + bn;          // bm
    float* f       = remainR + bm;          // bn
    float* c       = f + bn;                // bm
    float* costrow = c + bm;                // bn

    const float multiL = (float)((m / n > 1) ? (m / n) : 1);
    const float multiR = (float)((n / m > 1) ? (n / m) : 1);

    const int initN = bn > bm ? bn : bm;
    k_init<<<dim3((initN + BLOCK - 1) / BLOCK), dim3(BLOCK), 0, stream>>>(
        remainL, remainR, costrow, bn, bm, multiL, multiR);

    const int rpb = (BLOCK / 64) * RPW;     // 8 rows/cols per block
    dim3 rowGrid(bn / rpb), colGrid(bm / rpb), blk(BLOCK);
    const size_t ldsRow = (size_t)m * sizeof(float4);
    const size_t ldsCol = (size_t)n * sizeof(float4);
    const float L2E = 1.4426950408889634f;

    for (int t = 0; t < 10; ++t) {
        const int j = 7 - t;
        const float level = (t == 9) ? 0.f : -powf(4.f, (float)j);
        const float k = level * L2E;        // exp(level*d2) == exp2(k*d2)
        k_rowA<<<rowGrid, blk, ldsRow, stream>>>(xyz1, xyz2, remainL, remainR, f, n, m, k);
        k_colB<<<colGrid, blk, ldsCol, stream>>>(xyz1, xyz2, f, remainR, c, n, m, k);
        k_rowC<<<rowGrid, blk, ldsRow, stream>>>(xyz1, xyz2, f, c, remainL, costrow, n, m, k);
    }
    k_cost<<<dim3(b), blk, 0, stream>>>(costrow, out, n);
}